// Round 1
// baseline (329.043 us; speedup 1.0000x reference)
//
#include <hip/hip_runtime.h>

#define BB 4
#define NN 512
#define DD 16
#define EE 16
#define HH 128

// Kernel 1: proj_j[b,j,h] = sum_d node_feature[b,j,d] * W_edge[D+d][h]
__global__ void proj_j_kernel(const float* __restrict__ nf,
                              const float* __restrict__ W_edge,
                              float* __restrict__ pj) {
    int idx = blockIdx.x * 256 + threadIdx.x;
    if (idx >= BB * NN * HH) return;
    int h  = idx & (HH - 1);
    int bj = idx >> 7;
    const float* row = nf + bj * DD;
    float acc = 0.f;
#pragma unroll
    for (int d = 0; d < DD; ++d)
        acc = fmaf(row[d], W_edge[(DD + d) * HH + h], acc);
    pj[idx] = acc;
}

// Kernel 2: one block per (b,i). 128 threads: t&31 -> h-quad, t>>5 -> j-phase.
template <bool USE_WS>
__global__ __launch_bounds__(128, 4)
void fused_kernel(const float* __restrict__ node_feature,
                  const float* __restrict__ adjacency,
                  const float* __restrict__ edge_feature,
                  const float* __restrict__ W_edge,
                  const float* __restrict__ b_edge,
                  const float* __restrict__ W_feat,
                  const float* __restrict__ b_feat,
                  const float* __restrict__ pj,
                  float* __restrict__ out_end,
                  float* __restrict__ out_edge) {
    const int bi = blockIdx.x;           // b*N + i
    const int b  = bi >> 9;
    const int t  = threadIdx.x;          // 0..127
    const int hq = t & 31;
    const int jl = t >> 5;               // 0..3
    const int h0 = hq * 4;

    // We columns (rows 2D..2D+E-1 of W_edge) in registers: 64 VGPRs
    float4 we[EE];
#pragma unroll
    for (int e = 0; e < EE; ++e)
        we[e] = *(const float4*)(W_edge + (2 * DD + e) * HH + h0);

    float4 wj[USE_WS ? 1 : EE];
    if constexpr (!USE_WS) {
#pragma unroll
        for (int e = 0; e < EE; ++e)
            wj[e] = *(const float4*)(W_edge + (DD + e) * HH + h0);
    }

    // pi = b_edge + nf_i @ Wi   (own row i)
    const float* nfi = node_feature + bi * DD;
    float nfir[DD];
#pragma unroll
    for (int d4 = 0; d4 < DD; d4 += 4) {
        float4 v = *(const float4*)(nfi + d4);
        nfir[d4 + 0] = v.x; nfir[d4 + 1] = v.y;
        nfir[d4 + 2] = v.z; nfir[d4 + 3] = v.w;
    }
    float4 pi = *(const float4*)(b_edge + h0);
#pragma unroll
    for (int d = 0; d < DD; ++d) {
        float4 wi = *(const float4*)(W_edge + d * HH + h0);
        pi.x = fmaf(nfir[d], wi.x, pi.x);
        pi.y = fmaf(nfir[d], wi.y, pi.y);
        pi.z = fmaf(nfir[d], wi.z, pi.z);
        pi.w = fmaf(nfir[d], wi.w, pi.w);
    }

    const float* efb  = edge_feature + (size_t)bi * NN * EE;
    const float* adjr = adjacency + (size_t)bi * NN;
    const float* pjb  = pj + (b * NN) * HH;
    const float* nfb  = node_feature + (b * NN) * DD;
    float*       eob  = out_edge + (size_t)bi * NN * HH;

    float4 msg = make_float4(0.f, 0.f, 0.f, 0.f);

    for (int j = jl; j < NN; j += 4) {
        // edge_feature[b,i,j,0..15] (uniform within 32-lane group)
        float ef[EE];
#pragma unroll
        for (int e4 = 0; e4 < EE; e4 += 4) {
            float4 v = *(const float4*)(efb + j * EE + e4);
            ef[e4 + 0] = v.x; ef[e4 + 1] = v.y;
            ef[e4 + 2] = v.z; ef[e4 + 3] = v.w;
        }

        float4 acc;
        if constexpr (USE_WS) {
            float4 pjv = *(const float4*)(pjb + j * HH + h0);
            acc.x = pi.x + pjv.x;
            acc.y = pi.y + pjv.y;
            acc.z = pi.z + pjv.z;
            acc.w = pi.w + pjv.w;
        } else {
            acc = pi;
            const float* nfj = nfb + j * DD;
            float nr[DD];
#pragma unroll
            for (int d4 = 0; d4 < DD; d4 += 4) {
                float4 v = *(const float4*)(nfj + d4);
                nr[d4 + 0] = v.x; nr[d4 + 1] = v.y;
                nr[d4 + 2] = v.z; nr[d4 + 3] = v.w;
            }
#pragma unroll
            for (int d = 0; d < DD; ++d) {
                acc.x = fmaf(nr[d], wj[d].x, acc.x);
                acc.y = fmaf(nr[d], wj[d].y, acc.y);
                acc.z = fmaf(nr[d], wj[d].z, acc.z);
                acc.w = fmaf(nr[d], wj[d].w, acc.w);
            }
        }

#pragma unroll
        for (int e = 0; e < EE; ++e) {
            acc.x = fmaf(ef[e], we[e].x, acc.x);
            acc.y = fmaf(ef[e], we[e].y, acc.y);
            acc.z = fmaf(ef[e], we[e].z, acc.z);
            acc.w = fmaf(ef[e], we[e].w, acc.w);
        }
        acc.x = fmaxf(acc.x, 0.f);
        acc.y = fmaxf(acc.y, 0.f);
        acc.z = fmaxf(acc.z, 0.f);
        acc.w = fmaxf(acc.w, 0.f);

        *(float4*)(eob + (size_t)j * HH + h0) = acc;

        float a = adjr[j];
        msg.x = fmaf(a, acc.x, msg.x);
        msg.y = fmaf(a, acc.y, msg.y);
        msg.z = fmaf(a, acc.z, msg.z);
        msg.w = fmaf(a, acc.w, msg.w);
    }

    // Reduce message across the 4 j-phases, then ending = relu([msg,nf] @ W_feat + b_feat)
    __shared__ float msgred[4][HH];
    *(float4*)&msgred[jl][h0] = msg;
    __syncthreads();

    if (jl == 0) {
        float4 acc = *(const float4*)(b_feat + h0);
#pragma unroll 4
        for (int k = 0; k < HH; ++k) {
            float m = msgred[0][k] + msgred[1][k] + msgred[2][k] + msgred[3][k];
            float4 w = *(const float4*)(W_feat + k * HH + h0);
            acc.x = fmaf(m, w.x, acc.x);
            acc.y = fmaf(m, w.y, acc.y);
            acc.z = fmaf(m, w.z, acc.z);
            acc.w = fmaf(m, w.w, acc.w);
        }
#pragma unroll
        for (int d = 0; d < DD; ++d) {
            float m = nfir[d];
            float4 w = *(const float4*)(W_feat + (HH + d) * HH + h0);
            acc.x = fmaf(m, w.x, acc.x);
            acc.y = fmaf(m, w.y, acc.y);
            acc.z = fmaf(m, w.z, acc.z);
            acc.w = fmaf(m, w.w, acc.w);
        }
        acc.x = fmaxf(acc.x, 0.f);
        acc.y = fmaxf(acc.y, 0.f);
        acc.z = fmaxf(acc.z, 0.f);
        acc.w = fmaxf(acc.w, 0.f);
        *(float4*)(out_end + bi * HH + h0) = acc;
    }
}

extern "C" void kernel_launch(void* const* d_in, const int* in_sizes, int n_in,
                              void* d_out, int out_size, void* d_ws, size_t ws_size,
                              hipStream_t stream) {
    const float* node_feature = (const float*)d_in[0];
    const float* adjacency    = (const float*)d_in[1];
    const float* edge_feature = (const float*)d_in[2];
    // d_in[3] = node_mask (unused by reference math)
    const float* W_edge = (const float*)d_in[4];
    const float* b_edge = (const float*)d_in[5];
    const float* W_feat = (const float*)d_in[6];
    const float* b_feat = (const float*)d_in[7];

    float* out_end  = (float*)d_out;                       // (B,N,H) first
    float* out_edge = out_end + (size_t)BB * NN * HH;      // then (B,N,N,H)

    const size_t pj_bytes = (size_t)BB * NN * HH * sizeof(float);
    if (ws_size >= pj_bytes) {
        float* pj = (float*)d_ws;
        proj_j_kernel<<<(BB * NN * HH + 255) / 256, 256, 0, stream>>>(
            node_feature, W_edge, pj);
        fused_kernel<true><<<BB * NN, 128, 0, stream>>>(
            node_feature, adjacency, edge_feature, W_edge, b_edge,
            W_feat, b_feat, pj, out_end, out_edge);
    } else {
        fused_kernel<false><<<BB * NN, 128, 0, stream>>>(
            node_feature, adjacency, edge_feature, W_edge, b_edge,
            W_feat, b_feat, nullptr, out_end, out_edge);
    }
}

// Round 2
// 140.324 us; speedup vs baseline: 2.3449x; 2.3449x over previous
//
#include <hip/hip_runtime.h>

#define BB 4
#define NN 512
#define DD 16
#define EE 16
#define HH 128

typedef float f32x4 __attribute__((ext_vector_type(4)));

#define LD4(p) (*(const float4*)(p))

// Kernel 1: proj_j[b,j,h] = sum_d node_feature[b,j,d] * W_edge[D+d][h]
__global__ void proj_j_kernel(const float* __restrict__ nf,
                              const float* __restrict__ W_edge,
                              float* __restrict__ pj) {
    int idx = blockIdx.x * 256 + threadIdx.x;
    if (idx >= BB * NN * HH) return;
    int h  = idx & (HH - 1);
    int bj = idx >> 7;
    const float* row = nf + bj * DD;
    float acc = 0.f;
#pragma unroll
    for (int d = 0; d < DD; ++d)
        acc = fmaf(row[d], W_edge[(DD + d) * HH + h], acc);
    pj[idx] = acc;
}

// Kernel 2: one block per (b,i). 128 threads: t&31 -> h-quad, t>>5 -> j-phase.
// Manual 1-deep prefetch of next j's edge_feature/proj_j/adjacency.
template <bool USE_WS>
__global__ __launch_bounds__(128, 4)
void fused_kernel(const float* __restrict__ node_feature,
                  const float* __restrict__ adjacency,
                  const float* __restrict__ edge_feature,
                  const float* __restrict__ W_edge,
                  const float* __restrict__ b_edge,
                  const float* __restrict__ W_feat,
                  const float* __restrict__ b_feat,
                  const float* __restrict__ pj,
                  float* __restrict__ out_end,
                  float* __restrict__ out_edge) {
    const int bi = blockIdx.x;           // b*N + i
    const int b  = bi >> 9;
    const int t  = threadIdx.x;          // 0..127
    const int hq = t & 31;
    const int jl = t >> 5;               // 0..3
    const int h0 = hq * 4;

    // We columns (rows 2D..2D+E-1 of W_edge): keep in registers
    float4 we[EE];
#pragma unroll
    for (int e = 0; e < EE; ++e)
        we[e] = LD4(W_edge + (2 * DD + e) * HH + h0);

    float4 wj[USE_WS ? 1 : EE];
    if constexpr (!USE_WS) {
#pragma unroll
        for (int e = 0; e < EE; ++e)
            wj[e] = LD4(W_edge + (DD + e) * HH + h0);
    }

    // pi = b_edge + nf_i @ Wi   (own row i); nf_i NOT kept live through loop
    float4 pi = LD4(b_edge + h0);
    {
        const float* nfi = node_feature + bi * DD;
#pragma unroll
        for (int d4 = 0; d4 < DD; d4 += 4) {
            float4 v = LD4(nfi + d4);
            float nd[4] = {v.x, v.y, v.z, v.w};
#pragma unroll
            for (int q = 0; q < 4; ++q) {
                float4 wi = LD4(W_edge + (d4 + q) * HH + h0);
                pi.x = fmaf(nd[q], wi.x, pi.x);
                pi.y = fmaf(nd[q], wi.y, pi.y);
                pi.z = fmaf(nd[q], wi.z, pi.z);
                pi.w = fmaf(nd[q], wi.w, pi.w);
            }
        }
    }

    const float* efb  = edge_feature + (size_t)bi * NN * EE;
    const float* adjr = adjacency + (size_t)bi * NN;
    const float* pjb  = pj + (b * NN) * HH;
    const float* nfb  = node_feature + (b * NN) * DD;
    float*       eob  = out_edge + (size_t)bi * NN * HH;

    float4 msg = make_float4(0.f, 0.f, 0.f, 0.f);

    int j = jl;
    // prefetch iteration 0
    float4 efA0 = LD4(efb + j * EE + 0);
    float4 efA1 = LD4(efb + j * EE + 4);
    float4 efA2 = LD4(efb + j * EE + 8);
    float4 efA3 = LD4(efb + j * EE + 12);
    float4 pjA  = make_float4(0.f, 0.f, 0.f, 0.f);
    if constexpr (USE_WS) pjA = LD4(pjb + j * HH + h0);
    float  adjA = adjr[j];

    for (int it = 0; it < NN / 4; ++it) {
        const int jn = j + 4;
        const int jc = (jn < NN) ? jn : j;   // clamp prefetch addr (last iter)

        // ---- prefetch next iteration ----
        float4 efB0 = LD4(efb + jc * EE + 0);
        float4 efB1 = LD4(efb + jc * EE + 4);
        float4 efB2 = LD4(efb + jc * EE + 8);
        float4 efB3 = LD4(efb + jc * EE + 12);
        float4 pjB  = make_float4(0.f, 0.f, 0.f, 0.f);
        if constexpr (USE_WS) pjB = LD4(pjb + jc * HH + h0);
        float  adjB = adjr[jc];

        // ---- compute current ----
        float4 acc;
        if constexpr (USE_WS) {
            acc.x = pi.x + pjA.x;
            acc.y = pi.y + pjA.y;
            acc.z = pi.z + pjA.z;
            acc.w = pi.w + pjA.w;
        } else {
            acc = pi;
            const float* nfj = nfb + j * DD;
#pragma unroll
            for (int d = 0; d < DD; ++d) {
                float nv = nfj[d];
                acc.x = fmaf(nv, wj[d].x, acc.x);
                acc.y = fmaf(nv, wj[d].y, acc.y);
                acc.z = fmaf(nv, wj[d].z, acc.z);
                acc.w = fmaf(nv, wj[d].w, acc.w);
            }
        }

        float ef_[EE] = {efA0.x, efA0.y, efA0.z, efA0.w,
                         efA1.x, efA1.y, efA1.z, efA1.w,
                         efA2.x, efA2.y, efA2.z, efA2.w,
                         efA3.x, efA3.y, efA3.z, efA3.w};
#pragma unroll
        for (int e = 0; e < EE; ++e) {
            acc.x = fmaf(ef_[e], we[e].x, acc.x);
            acc.y = fmaf(ef_[e], we[e].y, acc.y);
            acc.z = fmaf(ef_[e], we[e].z, acc.z);
            acc.w = fmaf(ef_[e], we[e].w, acc.w);
        }
        acc.x = fmaxf(acc.x, 0.f);
        acc.y = fmaxf(acc.y, 0.f);
        acc.z = fmaxf(acc.z, 0.f);
        acc.w = fmaxf(acc.w, 0.f);

        // nontemporal store: don't write-allocate 537MB into L2/L3
        __builtin_nontemporal_store((f32x4){acc.x, acc.y, acc.z, acc.w},
                                    (f32x4*)(eob + (size_t)j * HH + h0));

        msg.x = fmaf(adjA, acc.x, msg.x);
        msg.y = fmaf(adjA, acc.y, msg.y);
        msg.z = fmaf(adjA, acc.z, msg.z);
        msg.w = fmaf(adjA, acc.w, msg.w);

        // rotate prefetch buffers
        efA0 = efB0; efA1 = efB1; efA2 = efB2; efA3 = efB3;
        pjA = pjB; adjA = adjB;
        j = jn;
    }

    // Reduce message across the 4 j-phases, then ending = relu([msg,nf] @ W_feat + b_feat)
    __shared__ float msgred[4][HH];
    *(float4*)&msgred[jl][h0] = msg;
    __syncthreads();

    if (jl == 0) {
        float4 acc = LD4(b_feat + h0);
#pragma unroll 4
        for (int k = 0; k < HH; ++k) {
            float m = msgred[0][k] + msgred[1][k] + msgred[2][k] + msgred[3][k];
            float4 w = LD4(W_feat + k * HH + h0);
            acc.x = fmaf(m, w.x, acc.x);
            acc.y = fmaf(m, w.y, acc.y);
            acc.z = fmaf(m, w.z, acc.z);
            acc.w = fmaf(m, w.w, acc.w);
        }
        const float* nfi = node_feature + bi * DD;
#pragma unroll
        for (int d = 0; d < DD; ++d) {
            float m = nfi[d];
            float4 w = LD4(W_feat + (HH + d) * HH + h0);
            acc.x = fmaf(m, w.x, acc.x);
            acc.y = fmaf(m, w.y, acc.y);
            acc.z = fmaf(m, w.z, acc.z);
            acc.w = fmaf(m, w.w, acc.w);
        }
        acc.x = fmaxf(acc.x, 0.f);
        acc.y = fmaxf(acc.y, 0.f);
        acc.z = fmaxf(acc.z, 0.f);
        acc.w = fmaxf(acc.w, 0.f);
        *(float4*)(out_end + bi * HH + h0) = acc;
    }
}

extern "C" void kernel_launch(void* const* d_in, const int* in_sizes, int n_in,
                              void* d_out, int out_size, void* d_ws, size_t ws_size,
                              hipStream_t stream) {
    const float* node_feature = (const float*)d_in[0];
    const float* adjacency    = (const float*)d_in[1];
    const float* edge_feature = (const float*)d_in[2];
    // d_in[3] = node_mask (unused by reference math)
    const float* W_edge = (const float*)d_in[4];
    const float* b_edge = (const float*)d_in[5];
    const float* W_feat = (const float*)d_in[6];
    const float* b_feat = (const float*)d_in[7];

    float* out_end  = (float*)d_out;                       // (B,N,H) first
    float* out_edge = out_end + (size_t)BB * NN * HH;      // then (B,N,N,H)

    const size_t pj_bytes = (size_t)BB * NN * HH * sizeof(float);
    if (ws_size >= pj_bytes) {
        float* pj = (float*)d_ws;
        proj_j_kernel<<<(BB * NN * HH + 255) / 256, 256, 0, stream>>>(
            node_feature, W_edge, pj);
        fused_kernel<true><<<BB * NN, 128, 0, stream>>>(
            node_feature, adjacency, edge_feature, W_edge, b_edge,
            W_feat, b_feat, pj, out_end, out_edge);
    } else {
        fused_kernel<false><<<BB * NN, 128, 0, stream>>>(
            node_feature, adjacency, edge_feature, W_edge, b_edge,
            W_feat, b_feat, nullptr, out_end, out_edge);
    }
}